// Round 1
// baseline (1432.573 us; speedup 1.0000x reference)
//
#include <hip/hip_runtime.h>
#include <stdint.h>

#define NGRP   2048       // BS*NWAY
#define NROWS  131072     // NGRP*NSHOT
#define DIM    512

typedef __bf16 bf16x8 __attribute__((ext_vector_type(8)));
typedef float  f32x4  __attribute__((ext_vector_type(4)));
typedef unsigned short ushort8 __attribute__((ext_vector_type(8)));
typedef unsigned short ushort4v __attribute__((ext_vector_type(4)));

// ws byte offsets
#define WS_WQ   0u
#define WS_WK   (512u*1024u)
#define WS_WV   (1024u*1024u)
#define WS_WR1  (1536u*1024u)
#define WS_Q    (2048u*1024u)
#define WS_K    (WS_Q + 134217728u)
#define WS_V    (WS_K + 134217728u)

__device__ __forceinline__ unsigned short f2bf(float x) {
  unsigned int u = __float_as_uint(x);
  u += 0x7fffu + ((u >> 16) & 1u);          // RNE
  return (unsigned short)(u >> 16);
}
__device__ __forceinline__ float bf2f(unsigned short b) {
  return __uint_as_float(((unsigned int)b) << 16);
}

// ---------------- K0: weight fp32 -> bf16 ----------------
__global__ void k_convert_w(const float* __restrict__ Wq, const float* __restrict__ Wk,
                            const float* __restrict__ Wv, const float* __restrict__ Wr1,
                            unsigned short* __restrict__ ws) {
  int i4 = (blockIdx.x * 256 + threadIdx.x) * 4;
  const float* src; unsigned short* dst; int off;
  if (i4 < 262144)      { src = Wq;  dst = ws;            off = i4; }
  else if (i4 < 524288) { src = Wk;  dst = ws + 262144;   off = i4 - 262144; }
  else if (i4 < 786432) { src = Wv;  dst = ws + 524288;   off = i4 - 524288; }
  else                  { src = Wr1; dst = ws + 786432;   off = i4 - 786432; }
  float4 v = *(const float4*)(src + off);
  ushort4v o;
  o[0] = f2bf(v.x); o[1] = f2bf(v.y); o[2] = f2bf(v.z); o[3] = f2bf(v.w);
  *(ushort4v*)(dst + off) = o;
}

// ---------------- K1: projection GEMM (q,k,v) ----------------
// C(131072x512) = X(131072x512,fp32) @ W^T(512x512,bf16) + bias, out bf16 to ws.
// 128x128 tile, BK=64, 4 waves (each 64x64), double-buffered swizzled LDS.
__launch_bounds__(256, 2)
__global__ void k_proj(const float* __restrict__ Xq, const float* __restrict__ Xk,
                       const float* __restrict__ Xv,
                       const unsigned short* __restrict__ wsw,   // bf16 weights base
                       const float* __restrict__ bq, const float* __restrict__ bk,
                       const float* __restrict__ bv,
                       unsigned short* __restrict__ wsout)       // ws base (ushort units)
{
  __shared__ __align__(16) unsigned char lds[65536]; // A0,A1 @0/16K ; B0,B1 @32K/48K
  const int tid  = threadIdx.x;
  const int lane = tid & 63;
  const int wid  = tid >> 6;
  const int bx   = blockIdx.x;
  const int p    = bx >> 12;        // projection id
  const int rem  = bx & 4095;
  const int nblk = rem & 3;         // N fastest -> A-tile reuse in L2/L3
  const int mblk = rem >> 2;

  const float* X; const unsigned short* W; const float* bias; unsigned short* outp;
  if (p == 0)      { X = Xq; W = wsw;          bias = bq; outp = wsout + WS_Q/2; }
  else if (p == 1) { X = Xk; W = wsw + 262144; bias = bk; outp = wsout + WS_K/2; }
  else             { X = Xv; W = wsw + 524288; bias = bv; outp = wsout + WS_V/2; }

  const int wm = (wid >> 1) * 64;
  const int wn = (wid & 1) * 64;

  auto stageA = [&](int buf, int kt) {
    const int r = tid >> 1, half = tid & 1;
    const float* src = X + (size_t)(mblk*128 + r)*512 + kt*64 + half*32;
    unsigned char* base = lds + buf*16384;
#pragma unroll
    for (int c2 = 0; c2 < 4; ++c2) {
      float4 v0 = *(const float4*)(src + c2*8);
      float4 v1 = *(const float4*)(src + c2*8 + 4);
      ushort8 o;
      o[0]=f2bf(v0.x); o[1]=f2bf(v0.y); o[2]=f2bf(v0.z); o[3]=f2bf(v0.w);
      o[4]=f2bf(v1.x); o[5]=f2bf(v1.y); o[6]=f2bf(v1.z); o[7]=f2bf(v1.w);
      int chunk = half*4 + c2;
      *(ushort8*)(base + r*128 + ((chunk*16) ^ ((r & 7) << 4))) = o;
    }
  };
  auto stageB = [&](int buf, int kt) {
    unsigned char* base = lds + 32768 + buf*16384;
#pragma unroll
    for (int i = 0; i < 4; ++i) {
      int ci = tid + i*256;                 // 0..1023
      int n = ci >> 3, c = ci & 7;
      ushort8 v = *(const ushort8*)(W + (size_t)(nblk*128 + n)*512 + kt*64 + c*8);
      *(ushort8*)(base + n*128 + ((c*16) ^ ((n & 7) << 4))) = v;
    }
  };

  f32x4 acc[4][4];
#pragma unroll
  for (int mt = 0; mt < 4; ++mt)
#pragma unroll
    for (int nt = 0; nt < 4; ++nt) acc[mt][nt] = (f32x4){0.f,0.f,0.f,0.f};

  stageA(0, 0); stageB(0, 0);
  __syncthreads();
  for (int kt = 0; kt < 8; ++kt) {
    int cur = kt & 1;
    if (kt < 7) { stageA(cur ^ 1, kt + 1); stageB(cur ^ 1, kt + 1); }
    const unsigned char* Ab = lds + cur*16384;
    const unsigned char* Bb = lds + 32768 + cur*16384;
#pragma unroll
    for (int ks = 0; ks < 2; ++ks) {
      int k0b = (ks*32 + ((lane >> 4) << 3)) * 2;   // byte offset in 128B row
      bf16x8 af[4], bfr[4];
#pragma unroll
      for (int mt = 0; mt < 4; ++mt) {
        int row = wm + mt*16 + (lane & 15);
        af[mt] = *(const bf16x8*)(Ab + row*128 + (k0b ^ ((row & 7) << 4)));
      }
#pragma unroll
      for (int nt = 0; nt < 4; ++nt) {
        int row = wn + nt*16 + (lane & 15);
        bfr[nt] = *(const bf16x8*)(Bb + row*128 + (k0b ^ ((row & 7) << 4)));
      }
#pragma unroll
      for (int mt = 0; mt < 4; ++mt)
#pragma unroll
        for (int nt = 0; nt < 4; ++nt)
          acc[mt][nt] = __builtin_amdgcn_mfma_f32_16x16x32_bf16(af[mt], bfr[nt], acc[mt][nt], 0, 0, 0);
    }
    __syncthreads();
  }

#pragma unroll
  for (int nt = 0; nt < 4; ++nt) {
    int col = nblk*128 + wn + nt*16 + (lane & 15);
    float b = bias[col];
#pragma unroll
    for (int mt = 0; mt < 4; ++mt)
#pragma unroll
      for (int r = 0; r < 4; ++r) {
        int row = mblk*128 + wm + mt*16 + ((lane >> 4) << 2) + r;
        outp[(size_t)row*512 + col] = f2bf(acc[mt][nt][r] + b);
      }
  }
}

// ---------------- K2: fused attention + reduce-MLP per (b,n) group ----------------
__launch_bounds__(256, 1)
__global__ void k_attn(const unsigned short* __restrict__ ws,
                       const float* __restrict__ br1,
                       const float* __restrict__ Wr2,
                       const float* __restrict__ br2,
                       float* __restrict__ out)
{
  __shared__ __align__(16) unsigned char KC[65536];   // k tile, later reused as context
  __shared__ __align__(16) unsigned char VT[65536];   // v^T  [h=512][j=64]
  __shared__ __align__(16) unsigned char ATT[8192];   // per-wave 16x64 att
  __shared__ float W64[64];
  const int tid = threadIdx.x, lane = tid & 63, wid = tid >> 6;
  const int g = blockIdx.x;
  const unsigned short* qp = ws + WS_Q/2 + (size_t)g*64*512;
  const unsigned short* kp = ws + WS_K/2 + (size_t)g*64*512;
  const unsigned short* vp = ws + WS_V/2 + (size_t)g*64*512;
  const unsigned short* wr1b = ws + WS_WR1/2;

  // stage k (swizzled rows of 1024B)
  for (int i = 0; i < 16; ++i) {
    int ci = tid + i*256;             // 0..4095
    int row = ci >> 6, hc = ci & 63;
    ushort8 v = *(const ushort8*)(kp + row*512 + hc*8);
    *(ushort8*)(KC + row*1024 + ((hc*16) ^ ((row & 7) << 4))) = v;
  }
  // stage v^T (swizzled rows of 128B)
  for (int i = 0; i < 16; ++i) {
    int ci = tid + i*256;
    int j = ci >> 6, hc = ci & 63;
    ushort8 v = *(const ushort8*)(vp + j*512 + hc*8);
#pragma unroll
    for (int e = 0; e < 8; ++e) {
      int h = hc*8 + e;
      *(unsigned short*)(VT + h*128 + ((j*2) ^ ((h & 7) << 4))) = v[e];
    }
  }
  // q fragments: wave strip rows [wid*16, wid*16+16)
  bf16x8 qf[16];
  {
    const unsigned short* qr = qp + (wid*16 + (lane & 15))*512 + ((lane >> 4) << 3);
#pragma unroll
    for (int kt = 0; kt < 16; ++kt) qf[kt] = *(const bf16x8*)(qr + kt*32);
  }
  __syncthreads();

  // scores = q @ k^T
  f32x4 sc[4];
#pragma unroll
  for (int nt = 0; nt < 4; ++nt) sc[nt] = (f32x4){0.f,0.f,0.f,0.f};
#pragma unroll
  for (int kt = 0; kt < 16; ++kt) {
    int k0b = (kt*32 + ((lane >> 4) << 3)) * 2;
#pragma unroll
    for (int nt = 0; nt < 4; ++nt) {
      int row = nt*16 + (lane & 15);
      bf16x8 kb = *(const bf16x8*)(KC + row*1024 + (k0b ^ ((row & 7) << 4)));
      sc[nt] = __builtin_amdgcn_mfma_f32_16x16x32_bf16(qf[kt], kb, sc[nt], 0, 0, 0);
    }
  }

  // softmax rows (each row lives in one 16-lane group, 4 nt regs)
  const float scale = 0.044194173824159216f;  // 1/sqrt(512)
#pragma unroll
  for (int r = 0; r < 4; ++r) {
    float a0 = sc[0][r]*scale, a1 = sc[1][r]*scale, a2 = sc[2][r]*scale, a3 = sc[3][r]*scale;
    float mx = fmaxf(fmaxf(a0, a1), fmaxf(a2, a3));
    mx = fmaxf(mx, __shfl_xor(mx, 1)); mx = fmaxf(mx, __shfl_xor(mx, 2));
    mx = fmaxf(mx, __shfl_xor(mx, 4)); mx = fmaxf(mx, __shfl_xor(mx, 8));
    float p0 = __expf(a0 - mx), p1 = __expf(a1 - mx), p2 = __expf(a2 - mx), p3 = __expf(a3 - mx);
    float s = p0 + p1 + p2 + p3;
    s += __shfl_xor(s, 1); s += __shfl_xor(s, 2); s += __shfl_xor(s, 4); s += __shfl_xor(s, 8);
    float inv = 1.f / s;
    int arow = ((lane >> 4) << 2) + r;
    unsigned char* ab = ATT + wid*2048 + arow*128;
    int sw = (arow & 7) << 4;
    *(unsigned short*)(ab + ((((lane & 15)      )*2) ^ sw)) = f2bf(p0*inv);
    *(unsigned short*)(ab + (((16 + (lane & 15))*2) ^ sw)) = f2bf(p1*inv);
    *(unsigned short*)(ab + (((32 + (lane & 15))*2) ^ sw)) = f2bf(p2*inv);
    *(unsigned short*)(ab + (((48 + (lane & 15))*2) ^ sw)) = f2bf(p3*inv);
  }
  __syncthreads();   // all scores-phase KC reads done; ATT visible

  // context = att @ v  (write bf16 context into KC, rows of wave's strip)
  {
    int arow = lane & 15;
    int aswz = (arow & 7) << 4;
    for (int ht = 0; ht < 32; ++ht) {
      f32x4 cc = (f32x4){0.f,0.f,0.f,0.f};
#pragma unroll
      for (int k2 = 0; k2 < 2; ++k2) {
        int j0b = (k2*32 + ((lane >> 4) << 3)) * 2;
        bf16x8 aatt = *(const bf16x8*)(ATT + wid*2048 + arow*128 + (j0b ^ aswz));
        int vrow = ht*16 + (lane & 15);
        bf16x8 bv8 = *(const bf16x8*)(VT + vrow*128 + (j0b ^ ((vrow & 7) << 4)));
        cc = __builtin_amdgcn_mfma_f32_16x16x32_bf16(aatt, bv8, cc, 0, 0, 0);
      }
#pragma unroll
      for (int r = 0; r < 4; ++r) {
        int crow = wid*16 + ((lane >> 4) << 2) + r;
        int colb = (ht*16 + (lane & 15)) * 2;
        *(unsigned short*)(KC + crow*1024 + (colb ^ ((crow & 7) << 4))) = f2bf(cc[r]);
      }
    }
  }
  __syncthreads();

  // hid = context @ Wr1^T + br1 ; leaky ; w = hid @ Wr2^T + br2
  f32x4 hid[4];
#pragma unroll
  for (int nt = 0; nt < 4; ++nt) hid[nt] = (f32x4){0.f,0.f,0.f,0.f};
  {
    int crow = wid*16 + (lane & 15);
    int cswz = (crow & 7) << 4;
    const unsigned char* cb = KC + crow*1024;
#pragma unroll
    for (int kt = 0; kt < 16; ++kt) {
      int k0b = (kt*32 + ((lane >> 4) << 3)) * 2;
      bf16x8 a = *(const bf16x8*)(cb + (k0b ^ cswz));
#pragma unroll
      for (int nt = 0; nt < 4; ++nt) {
        bf16x8 b = *(const bf16x8*)(wr1b + (nt*16 + (lane & 15))*512 + kt*32 + ((lane >> 4) << 3));
        hid[nt] = __builtin_amdgcn_mfma_f32_16x16x32_bf16(a, b, hid[nt], 0, 0, 0);
      }
    }
  }
  float wpart[4] = {0.f, 0.f, 0.f, 0.f};
#pragma unroll
  for (int nt = 0; nt < 4; ++nt) {
    int mcol = nt*16 + (lane & 15);
    float bb = br1[mcol];
    float w2 = Wr2[mcol];
#pragma unroll
    for (int r = 0; r < 4; ++r) {
      float h = hid[nt][r] + bb;
      h = h >= 0.f ? h : 0.01f * h;
      wpart[r] += h * w2;
    }
  }
  float b2 = br2[0];
#pragma unroll
  for (int r = 0; r < 4; ++r) {
    float t = wpart[r];
    t += __shfl_xor(t, 1); t += __shfl_xor(t, 2); t += __shfl_xor(t, 4); t += __shfl_xor(t, 8);
    if ((lane & 15) == 0) W64[wid*16 + ((lane >> 4) << 2) + r] = t + b2;
  }
  __syncthreads();

  // out[h] = sum_i context[i,h] * w[i]
  {
    int h0 = tid * 2;
    float a0 = 0.f, a1 = 0.f;
    for (int i = 0; i < 64; ++i) {
      float wi = W64[i];
      unsigned int u = *(const unsigned int*)(KC + i*1024 + ((h0*2) ^ ((i & 7) << 4)));
      a0 += wi * bf2f((unsigned short)(u & 0xffffu));
      a1 += wi * bf2f((unsigned short)(u >> 16));
    }
    float2 o; o.x = a0; o.y = a1;
    *(float2*)(out + (size_t)g*512 + h0) = o;
  }
}

extern "C" void kernel_launch(void* const* d_in, const int* in_sizes, int n_in,
                              void* d_out, int out_size, void* d_ws, size_t ws_size,
                              hipStream_t stream) {
  const float* query = (const float*)d_in[0];
  const float* key   = (const float*)d_in[1];
  const float* value = (const float*)d_in[2];
  const float* Wq  = (const float*)d_in[3];
  const float* bq  = (const float*)d_in[4];
  const float* Wk  = (const float*)d_in[5];
  const float* bk  = (const float*)d_in[6];
  const float* Wv  = (const float*)d_in[7];
  const float* bv  = (const float*)d_in[8];
  const float* Wr1 = (const float*)d_in[9];
  const float* br1 = (const float*)d_in[10];
  const float* Wr2 = (const float*)d_in[11];
  const float* br2 = (const float*)d_in[12];
  unsigned short* ws = (unsigned short*)d_ws;
  float* out = (float*)d_out;

  hipLaunchKernelGGL(k_convert_w, dim3(800), dim3(256), 0, stream, Wq, Wk, Wv, Wr1, ws);
  hipLaunchKernelGGL(k_proj, dim3(12288), dim3(256), 0, stream,
                     query, key, value, ws, bq, bk, bv, ws);
  hipLaunchKernelGGL(k_attn, dim3(2048), dim3(256), 0, stream, ws, br1, Wr2, br2, out);
}

// Round 2
// 1112.333 us; speedup vs baseline: 1.2879x; 1.2879x over previous
//
#include <hip/hip_runtime.h>
#include <stdint.h>

typedef __bf16 bf16x8 __attribute__((ext_vector_type(8)));
typedef float  f32x4  __attribute__((ext_vector_type(4)));

// ws byte offsets
#define WS_J     0u
#define WS_WVT   524288u
#define WS_W1    1048576u
#define WS_U     1114112u
#define WS_BR1P  1116160u
#define WS_QQ    2097152u
#define WS_POOL  136314880u
#define WS_SUMW  140509184u

__device__ __forceinline__ float bf2f(unsigned short b) {
  return __uint_as_float(((unsigned int)b) << 16);
}

// ---------------- K0: precompute folded weights ----------------
// J[h][d] = sum_m Wk[m][h]*Wq[m][d] / sqrt(512)      (bf16)
// u[h]    = sum_m Wk[m][h]*bq[m] / sqrt(512)          (fp32)
// WvT[h][ho] = Wv[ho][h]                              (bf16)
// W1[m][d] = sum_h Wr1[m][h]*Wv[h][d]                 (bf16)
// br1p[m]  = br1[m] + sum_h Wr1[m][h]*bv[h]           (fp32)
__global__ void k_prep(const float* __restrict__ Wq, const float* __restrict__ bq,
                       const float* __restrict__ Wk, const float* __restrict__ Wv,
                       const float* __restrict__ bv, const float* __restrict__ Wr1,
                       const float* __restrict__ br1, char* __restrict__ wsb)
{
  const int tid = threadIdx.x;
  __bf16* Jb  = (__bf16*)(wsb + WS_J);
  __bf16* WvT = (__bf16*)(wsb + WS_WVT);
  __bf16* W1b = (__bf16*)(wsb + WS_W1);
  float*  ub  = (float*)(wsb + WS_U);
  float*  b1p = (float*)(wsb + WS_BR1P);
  const float invs = 0.044194173824159216f;  // 1/sqrt(512)
  int b = blockIdx.x;
  if (b < 512) {
    int h = b;
    float a0 = 0.f, a1 = 0.f, au = 0.f;
    for (int m = 0; m < 512; ++m) {
      float wk = Wk[m*512 + h];
      a0 = fmaf(wk, Wq[m*512 + tid], a0);
      a1 = fmaf(wk, Wq[m*512 + tid + 256], a1);
      if (tid == 0) au = fmaf(wk, bq[m], au);
    }
    Jb[h*512 + tid]       = (__bf16)(a0 * invs);
    Jb[h*512 + tid + 256] = (__bf16)(a1 * invs);
    if (tid == 0) ub[h] = au * invs;
    WvT[h*512 + tid]       = (__bf16)Wv[(size_t)tid*512 + h];
    WvT[h*512 + tid + 256] = (__bf16)Wv[(size_t)(tid+256)*512 + h];
  } else {
    int m = b - 512;   // 0..63
    float a0 = 0.f, a1 = 0.f, ab = 0.f;
    for (int h = 0; h < 512; ++h) {
      float wr = Wr1[m*512 + h];
      a0 = fmaf(wr, Wv[h*512 + tid], a0);
      a1 = fmaf(wr, Wv[h*512 + tid + 256], a1);
      if (tid == 0) ab = fmaf(wr, bv[h], ab);
    }
    W1b[m*512 + tid]       = (__bf16)a0;
    W1b[m*512 + tid + 256] = (__bf16)a1;
    if (tid == 0) b1p[m] = br1[m] + ab;
  }
}

// ---------------- K1: qq = X_q @ J^T (131072x512x512), bf16 out ----------------
// 128x128 tile, BK=64, 4 waves, double-buffered swizzled LDS, T14 async-stage.
__launch_bounds__(256, 2)
__global__ void k_qq(const float* __restrict__ X, const char* __restrict__ wsb,
                     char* __restrict__ wsout)
{
  __shared__ __align__(16) unsigned char lds[65536]; // A0,A1 @0/16K ; B0,B1 @32K/48K
  const int tid = threadIdx.x, lane = tid & 63, wid = tid >> 6;
  const int swz  = (blockIdx.x & 7) * 512 + (blockIdx.x >> 3);  // XCD swizzle (4096 % 8 == 0)
  const int nblk = swz & 3, mblk = swz >> 2;
  const __bf16* J = (const __bf16*)(wsb + WS_J);
  __bf16* outp = (__bf16*)(wsout + WS_QQ);
  const int wm = (wid >> 1) * 64, wn = (wid & 1) * 64;
  const int r_ = tid >> 1, half = tid & 1;

  float4 ar[8];
  bf16x8 brg[4];

  auto loadA = [&](int kt) {
    const float* src = X + (size_t)(mblk*128 + r_)*512 + kt*64 + half*32;
#pragma unroll
    for (int c = 0; c < 8; ++c) ar[c] = *(const float4*)(src + c*4);
  };
  auto writeA = [&](int buf) {
    unsigned char* base = lds + buf*16384;
#pragma unroll
    for (int c2 = 0; c2 < 4; ++c2) {
      bf16x8 o;
      o[0]=(__bf16)ar[c2*2].x; o[1]=(__bf16)ar[c2*2].y;
      o[2]=(__bf16)ar[c2*2].z; o[3]=(__bf16)ar[c2*2].w;
      o[4]=(__bf16)ar[c2*2+1].x; o[5]=(__bf16)ar[c2*2+1].y;
      o[6]=(__bf16)ar[c2*2+1].z; o[7]=(__bf16)ar[c2*2+1].w;
      int chunk = half*4 + c2;
      *(bf16x8*)(base + r_*128 + ((chunk*16) ^ ((r_ & 7) << 4))) = o;
    }
  };
  auto loadB = [&](int kt) {
#pragma unroll
    for (int i = 0; i < 4; ++i) {
      int ci = tid + i*256; int n = ci >> 3, c = ci & 7;
      brg[i] = *(const bf16x8*)(J + (size_t)(nblk*128 + n)*512 + kt*64 + c*8);
    }
  };
  auto writeB = [&](int buf) {
    unsigned char* base = lds + 32768 + buf*16384;
#pragma unroll
    for (int i = 0; i < 4; ++i) {
      int ci = tid + i*256; int n = ci >> 3, c = ci & 7;
      *(bf16x8*)(base + n*128 + ((c*16) ^ ((n & 7) << 4))) = brg[i];
    }
  };

  f32x4 acc[4][4];
#pragma unroll
  for (int mt = 0; mt < 4; ++mt)
#pragma unroll
    for (int nt = 0; nt < 4; ++nt) acc[mt][nt] = (f32x4){0.f,0.f,0.f,0.f};

  loadA(0); loadB(0); writeA(0); writeB(0);
  __syncthreads();
  for (int kt = 0; kt < 8; ++kt) {
    int cur = kt & 1;
    if (kt < 7) { loadA(kt + 1); loadB(kt + 1); }   // issue loads early (T14)
    const unsigned char* Ab = lds + cur*16384;
    const unsigned char* Bb = lds + 32768 + cur*16384;
#pragma unroll
    for (int ks = 0; ks < 2; ++ks) {
      int k0b = (ks*32 + ((lane >> 4) << 3)) * 2;
      bf16x8 af[4], bfr[4];
#pragma unroll
      for (int mt = 0; mt < 4; ++mt) {
        int row = wm + mt*16 + (lane & 15);
        af[mt] = *(const bf16x8*)(Ab + row*128 + (k0b ^ ((row & 7) << 4)));
      }
#pragma unroll
      for (int nt = 0; nt < 4; ++nt) {
        int row = wn + nt*16 + (lane & 15);
        bfr[nt] = *(const bf16x8*)(Bb + row*128 + (k0b ^ ((row & 7) << 4)));
      }
#pragma unroll
      for (int mt = 0; mt < 4; ++mt)
#pragma unroll
        for (int nt = 0; nt < 4; ++nt)
          acc[mt][nt] = __builtin_amdgcn_mfma_f32_16x16x32_bf16(af[mt], bfr[nt], acc[mt][nt], 0, 0, 0);
    }
    if (kt < 7) { writeA(cur ^ 1); writeB(cur ^ 1); }  // convert+write late
    __syncthreads();
  }

#pragma unroll
  for (int nt = 0; nt < 4; ++nt) {
    int col = nblk*128 + wn + nt*16 + (lane & 15);
#pragma unroll
    for (int mt = 0; mt < 4; ++mt)
#pragma unroll
      for (int r = 0; r < 4; ++r) {
        int row = mblk*128 + wm + mt*16 + ((lane >> 4) << 2) + r;
        outp[(size_t)row*512 + col] = (__bf16)acc[mt][nt][r];
      }
  }
}

// ---------------- K2: per-(b,n) fused attention (folded algebra) ----------------
// scores = qq @ X_k^T + beta ; att = softmax ; rc = att @ X_v ;
// hid = rc@W1^T + br1p ; leaky ; w = hid@Wr2 + br2 ; pooled = w^T rc ; sumw.
__launch_bounds__(512, 2)
__global__ void k_attn(const float* __restrict__ Xk, const float* __restrict__ Xv,
                       const char* __restrict__ wsb, const float* __restrict__ Wr2,
                       const float* __restrict__ br2, char* __restrict__ wso)
{
  __shared__ __align__(16) unsigned char KX[65536];   // X_k bf16 [64][1024B swz] -> later rc
  __shared__ __align__(16) unsigned char XV[65536];   // X_v^T bf16 [512 h][128B swz]
  __shared__ float SATT[64][68];                      // scores / normalized p (fp32)
  __shared__ float BETA[64];
  __shared__ float PW[2][64];
  __shared__ float W64[64];
  const int tid = threadIdx.x, lane = tid & 63, wid = tid >> 6;
  const int g = blockIdx.x;
  const __bf16* qq  = (const __bf16*)(wsb + WS_QQ) + (size_t)g*64*512;
  const __bf16* W1b = (const __bf16*)(wsb + WS_W1);
  const float* ub   = (const float*)(wsb + WS_U);
  const float* b1p  = (const float*)(wsb + WS_BR1P);
  float* pooled = (float*)(wso + WS_POOL) + (size_t)g*512;
  float* sumw   = (float*)(wso + WS_SUMW);

  // ---- P0: stage KX + beta, stage XV (transposed) ----
  {
    const int row = tid >> 3, c0 = tid & 7;
    const float* src = Xk + ((size_t)g*64 + row)*512;
    float bp = 0.f;
#pragma unroll
    for (int i = 0; i < 8; ++i) {
      int c = c0 + i*8;
      float4 v0 = *(const float4*)(src + c*8);
      float4 v1 = *(const float4*)(src + c*8 + 4);
      float4 u0 = *(const float4*)(ub + c*8);
      float4 u1 = *(const float4*)(ub + c*8 + 4);
      bp += v0.x*u0.x + v0.y*u0.y + v0.z*u0.z + v0.w*u0.w
          + v1.x*u1.x + v1.y*u1.y + v1.z*u1.z + v1.w*u1.w;
      bf16x8 o;
      o[0]=(__bf16)v0.x; o[1]=(__bf16)v0.y; o[2]=(__bf16)v0.z; o[3]=(__bf16)v0.w;
      o[4]=(__bf16)v1.x; o[5]=(__bf16)v1.y; o[6]=(__bf16)v1.z; o[7]=(__bf16)v1.w;
      *(bf16x8*)(KX + row*1024 + ((c*16) ^ ((row & 7) << 4))) = o;
    }
    bp += __shfl_xor(bp, 1); bp += __shfl_xor(bp, 2); bp += __shfl_xor(bp, 4);
    if ((tid & 7) == 0) BETA[row] = bp;

    const int j = row;
    const float* vsrc = Xv + ((size_t)g*64 + j)*512;
#pragma unroll
    for (int i = 0; i < 8; ++i) {
      int hc = c0 + i*8;
      float4 v0 = *(const float4*)(vsrc + hc*8);
      float4 v1 = *(const float4*)(vsrc + hc*8 + 4);
      float vv[8] = {v0.x,v0.y,v0.z,v0.w,v1.x,v1.y,v1.z,v1.w};
#pragma unroll
      for (int e = 0; e < 8; ++e) {
        int h = hc*8 + e;
        int sh = ((h >> 3) & 7) ^ (h & 7);
        *(__bf16*)(XV + h*128 + ((j*2) ^ (sh << 4))) = (__bf16)vv[e];
      }
    }
  }
  __syncthreads();

  // ---- P1: scores = qq @ KX^T ; write fp32 to SATT ----
  {
    const int ms = wid >> 1, np = wid & 1;
    bf16x8 qf[16];
    const __bf16* qrow = qq + (ms*16 + (lane & 15))*512 + ((lane >> 4) << 3);
#pragma unroll
    for (int kt = 0; kt < 16; ++kt) qf[kt] = *(const bf16x8*)(qrow + kt*32);
    f32x4 s0 = (f32x4){0.f,0.f,0.f,0.f}, s1 = s0;
#pragma unroll
    for (int kt = 0; kt < 16; ++kt) {
      int k0b = (kt*32 + ((lane >> 4) << 3)) * 2;
      int r0 = (np*2)*16 + (lane & 15);
      int r1 = (np*2+1)*16 + (lane & 15);
      bf16x8 b0 = *(const bf16x8*)(KX + r0*1024 + (k0b ^ ((r0 & 7) << 4)));
      bf16x8 b1 = *(const bf16x8*)(KX + r1*1024 + (k0b ^ ((r1 & 7) << 4)));
      s0 = __builtin_amdgcn_mfma_f32_16x16x32_bf16(qf[kt], b0, s0, 0, 0, 0);
      s1 = __builtin_amdgcn_mfma_f32_16x16x32_bf16(qf[kt], b1, s1, 0, 0, 0);
    }
#pragma unroll
    for (int r = 0; r < 4; ++r) {
      int row = ms*16 + ((lane >> 4) << 2) + r;
      SATT[row][(np*2)*16   + (lane & 15)] = s0[r];
      SATT[row][(np*2+1)*16 + (lane & 15)] = s1[r];
    }
  }
  __syncthreads();

  // ---- P2: wave-parallel softmax (8 rows per wave, 64 lanes = 64 cols) ----
  {
#pragma unroll
    for (int rr = 0; rr < 8; ++rr) {
      int row = wid*8 + rr;
      float v = SATT[row][lane] + BETA[lane];
      float m = v;
      m = fmaxf(m, __shfl_xor(m, 1));  m = fmaxf(m, __shfl_xor(m, 2));
      m = fmaxf(m, __shfl_xor(m, 4));  m = fmaxf(m, __shfl_xor(m, 8));
      m = fmaxf(m, __shfl_xor(m, 16)); m = fmaxf(m, __shfl_xor(m, 32));
      float p = __expf(v - m);
      float s = p;
      s += __shfl_xor(s, 1);  s += __shfl_xor(s, 2);  s += __shfl_xor(s, 4);
      s += __shfl_xor(s, 8);  s += __shfl_xor(s, 16); s += __shfl_xor(s, 32);
      SATT[row][lane] = p / s;
    }
  }
  __syncthreads();

  // ---- P3: rc = att @ X_v ; write bf16 rc into KX ----
  {
    const int ms = wid & 3, hh = wid >> 2;
    bf16x8 pa[2];
#pragma unroll
    for (int ks = 0; ks < 2; ++ks) {
      int arow = ms*16 + (lane & 15);
      const float* pp = &SATT[arow][ks*32 + ((lane >> 4) << 3)];
      f32x4 p0 = *(const f32x4*)pp;
      f32x4 p1 = *(const f32x4*)(pp + 4);
      bf16x8 o;
      o[0]=(__bf16)p0[0]; o[1]=(__bf16)p0[1]; o[2]=(__bf16)p0[2]; o[3]=(__bf16)p0[3];
      o[4]=(__bf16)p1[0]; o[5]=(__bf16)p1[1]; o[6]=(__bf16)p1[2]; o[7]=(__bf16)p1[3];
      pa[ks] = o;
    }
#pragma unroll
    for (int ht = 0; ht < 16; ++ht) {
      f32x4 cc = (f32x4){0.f,0.f,0.f,0.f};
#pragma unroll
      for (int ks = 0; ks < 2; ++ks) {
        int vrow = hh*256 + ht*16 + (lane & 15);
        int shv = ((vrow >> 3) & 7) ^ (vrow & 7);
        bf16x8 vb = *(const bf16x8*)(XV + vrow*128 +
                      (((ks*32 + ((lane >> 4) << 3)) * 2) ^ (shv << 4)));
        cc = __builtin_amdgcn_mfma_f32_16x16x32_bf16(pa[ks], vb, cc, 0, 0, 0);
      }
#pragma unroll
      for (int r = 0; r < 4; ++r) {
        int crow = ms*16 + ((lane >> 4) << 2) + r;
        int h = hh*256 + ht*16 + (lane & 15);
        *(__bf16*)(KX + crow*1024 + (((h >> 3) << 4) ^ ((crow & 7) << 4)) + (h & 7)*2)
            = (__bf16)cc[r];
      }
    }
  }
  __syncthreads();

  // ---- P4: hid = rc @ W1^T + br1p ; leaky ; per-row w partials ----
  {
    const int ms = wid >> 1, np = wid & 1;
    f32x4 h0 = (f32x4){0.f,0.f,0.f,0.f}, h1 = h0;
    int arow = ms*16 + (lane & 15);
    const unsigned char* ab = KX + arow*1024;
    int asw = (arow & 7) << 4;
#pragma unroll
    for (int kt = 0; kt < 16; ++kt) {
      int d2 = (kt*32 + ((lane >> 4) << 3)) * 2;
      bf16x8 a = *(const bf16x8*)(ab + (d2 ^ asw));
      const __bf16* wb = W1b + kt*32 + ((lane >> 4) << 3);
      bf16x8 b0 = *(const bf16x8*)(wb + (size_t)(np*32 + (lane & 15))*512);
      bf16x8 b1 = *(const bf16x8*)(wb + (size_t)(np*32 + 16 + (lane & 15))*512);
      h0 = __builtin_amdgcn_mfma_f32_16x16x32_bf16(a, b0, h0, 0, 0, 0);
      h1 = __builtin_amdgcn_mfma_f32_16x16x32_bf16(a, b1, h1, 0, 0, 0);
    }
    int m0 = np*32 + (lane & 15), m1 = m0 + 16;
    float bb0 = b1p[m0], bb1 = b1p[m1];
    float w20 = Wr2[m0], w21 = Wr2[m1];
#pragma unroll
    for (int r = 0; r < 4; ++r) {
      float x0 = h0[r] + bb0; x0 = x0 >= 0.f ? x0 : 0.01f*x0;
      float x1 = h1[r] + bb1; x1 = x1 >= 0.f ? x1 : 0.01f*x1;
      float t = x0*w20 + x1*w21;
      t += __shfl_xor(t, 1); t += __shfl_xor(t, 2);
      t += __shfl_xor(t, 4); t += __shfl_xor(t, 8);
      if ((lane & 15) == 0) PW[np][ms*16 + ((lane >> 4) << 2) + r] = t;
    }
  }
  __syncthreads();

  // ---- P5: finalize w, sumw ----
  if (tid < 64) {
    float wv = PW[0][tid] + PW[1][tid] + br2[0];
    W64[tid] = wv;
    float s = wv;
    s += __shfl_xor(s, 1);  s += __shfl_xor(s, 2);  s += __shfl_xor(s, 4);
    s += __shfl_xor(s, 8);  s += __shfl_xor(s, 16); s += __shfl_xor(s, 32);
    if (tid == 0) sumw[g] = s;
  }
  __syncthreads();

  // ---- P6: pooled[h] = sum_i w[i] * rc[i][h] ----
  {
    int h = tid;
    float acc = 0.f;
#pragma unroll 8
    for (int i = 0; i < 64; ++i) {
      unsigned short uv = *(const unsigned short*)(KX + i*1024 +
          (((h >> 3) << 4) ^ ((i & 7) << 4)) + (h & 7)*2);
      acc = fmaf(W64[i], bf2f(uv), acc);
    }
    pooled[h] = acc;
  }
}

// ---------------- K3: out = pooled @ Wv^T + sumw*bv ----------------
__launch_bounds__(256, 4)
__global__ void k_out(const char* __restrict__ wsb, const float* __restrict__ bv,
                      float* __restrict__ out)
{
  __shared__ float PL[512];
  const int tid = threadIdx.x, g = blockIdx.x;
  const float* pooled = (const float*)(wsb + WS_POOL) + (size_t)g*512;
  const __bf16* WvT = (const __bf16*)(wsb + WS_WVT);
  float sw = ((const float*)(wsb + WS_SUMW))[g];
  PL[tid] = pooled[tid]; PL[tid + 256] = pooled[tid + 256];
  __syncthreads();
  float a0 = 0.f, a1 = 0.f;
  for (int h = 0; h < 512; ++h) {
    float pl = PL[h];
    a0 = fmaf(pl, (float)WvT[(size_t)h*512 + tid], a0);
    a1 = fmaf(pl, (float)WvT[(size_t)h*512 + tid + 256], a1);
  }
  out[(size_t)g*512 + tid]       = a0 + sw*bv[tid];
  out[(size_t)g*512 + tid + 256] = a1 + sw*bv[tid + 256];
}

extern "C" void kernel_launch(void* const* d_in, const int* in_sizes, int n_in,
                              void* d_out, int out_size, void* d_ws, size_t ws_size,
                              hipStream_t stream) {
  const float* query = (const float*)d_in[0];
  const float* key   = (const float*)d_in[1];
  const float* value = (const float*)d_in[2];
  const float* Wq  = (const float*)d_in[3];
  const float* bq  = (const float*)d_in[4];
  const float* Wk  = (const float*)d_in[5];
  const float* bk  = (const float*)d_in[6];  (void)bk;  // softmax-invariant, dropped
  const float* Wv  = (const float*)d_in[7];
  const float* bv  = (const float*)d_in[8];
  const float* Wr1 = (const float*)d_in[9];
  const float* br1 = (const float*)d_in[10];
  const float* Wr2 = (const float*)d_in[11];
  const float* br2 = (const float*)d_in[12];
  char* wsb = (char*)d_ws;
  float* out = (float*)d_out;

  hipLaunchKernelGGL(k_prep, dim3(576),  dim3(256), 0, stream,
                     Wq, bq, Wk, Wv, bv, Wr1, br1, wsb);
  hipLaunchKernelGGL(k_qq,   dim3(4096), dim3(256), 0, stream, query, wsb, wsb);
  hipLaunchKernelGGL(k_attn, dim3(2048), dim3(512), 0, stream,
                     key, value, wsb, Wr2, br2, wsb);
  hipLaunchKernelGGL(k_out,  dim3(2048), dim3(256), 0, stream, wsb, bv, out);
}